// Round 7
// baseline (149.430 us; speedup 1.0000x reference)
//
#include <hip/hip_runtime.h>
#include <hip/hip_bf16.h>

// ---------------------------------------------------------------------------
// Def_DownSampling, round 7.
//  * gaus_w identical per (oc,ic) => gaussian path uses channel-summed field.
//  * conv3+avgpool folded to stride-2 4^3 conv (W4), exact algebra.
//  * D via bf16 MFMA; Dsum kept fp32 (fused VALU dot) for the grid path.
//  * R7: fixes R6's boundary-window-shift bug. Direct-global taps per lane
//    (4x float4/ic), boundary handled by shift-masks mc/ml/mr:
//    r[c] = mc*ld[c] + ml*ld[c-1] + mr*ld[c+1]  (exact 0/1 coefficients).
// Outputs: y (2,32,32,32,32) | D (2,32,32,32,32) | grid-mean (2,32,32,32,3)
// ---------------------------------------------------------------------------

#define XN 64
#define DN 32
#define C  32
#define XVOL (XN * XN * XN)   // 262144
#define DVOL (DN * DN * DN)   // 32768

typedef __attribute__((ext_vector_type(8))) short short8v;
typedef __attribute__((ext_vector_type(4))) float float4v;

struct __attribute__((packed, aligned(4))) f4u { float4v v; };
struct __attribute__((packed, aligned(4))) s8u { short8v v; };

static __device__ __forceinline__ short f2bf(float f) {
    union { float f; unsigned u; } v; v.f = f;
    unsigned r = (v.u + 0x7fffu + ((v.u >> 16) & 1u)) >> 16;   // RNE
    return (short)r;
}

static __device__ __forceinline__ unsigned pk2(float a, float b) {
    __hip_bfloat162 h = __float22bfloat162_rn(float2{a, b});
    union { __hip_bfloat162 h2; unsigned u; } cv; cv.h2 = h;
    return cv.u;
}

// shifted-masked taps: out[c] = mc*ld[c] + ml*ld[c-1] + mr*ld[c+1]
static __device__ __forceinline__ float4v shmask(float4v ld, float c, float l, float r) {
    float4v o;
    o[0] = fmaf(r, ld[1], c * ld[0]);
    o[1] = fmaf(l, ld[0], fmaf(r, ld[2], c * ld[1]));
    o[2] = fmaf(l, ld[1], fmaf(r, ld[3], c * ld[2]));
    o[3] = fmaf(l, ld[2], c * ld[3]);
    return o;
}

// W4[ic][u][oc] = (1/8) sum_{s in {0,1}^3} conv_w[oc][ic][u-s]
static __device__ __forceinline__ float w4val(const float* __restrict__ conv_w,
                                              int ic, int u, int oc) {
    int uz = u >> 4, uy = (u >> 2) & 3, ux = u & 3;
    float s = 0.f;
    #pragma unroll
    for (int sz = 0; sz < 2; ++sz) {
        int tz = uz - sz; if (tz < 0 || tz > 2) continue;
        #pragma unroll
        for (int sy = 0; sy < 2; ++sy) {
            int ty = uy - sy; if (ty < 0 || ty > 2) continue;
            #pragma unroll
            for (int sx = 0; sx < 2; ++sx) {
                int tx = ux - sx; if (tx < 0 || tx > 2) continue;
                s += conv_w[(oc * C + ic) * 27 + tz * 9 + ty * 3 + tx];
            }
        }
    }
    return 0.125f * s;
}

// ---- K0: blocks 0..255 pack A-fragments (bf16) + biassum;
//          blocks 256..511 compute wsum[k] = sum_oc W4[k][oc] via shfl tree.
__global__ __launch_bounds__(256) void k_prep(const float* __restrict__ conv_w,
                                              const float* __restrict__ conv_b,
                                              unsigned short* __restrict__ wfrag,
                                              float* __restrict__ wsum) {
    int bid = blockIdx.x;
    int tid = threadIdx.x;
    if (bid < 256) {
        int i = bid * 256 + tid;                // 65536
        int e = i & 7;
        int l = (i >> 3) & 63;
        int sf = i >> 9;
        int f = sf & 1, step = sf >> 1;
        int oc = f * 16 + (l & 15);
        int k = step * 32 + ((l >> 4) * 8 + e);
        float v = w4val(conv_w, k >> 6, k & 63, oc);
        wfrag[i] = (unsigned short)f2bf(v);
        if (i == 0) {
            float s = 0.f;
            for (int o = 0; o < C; ++o) s += conv_b[o];
            wsum[2048] = s;
        }
    } else {
        int i2 = (bid - 256) * 256 + tid;       // 65536 = 2048 k x 32 oc
        int oc = tid & 31;
        int kk = i2 >> 5;
        float v = w4val(conv_w, kk >> 6, kk & 63, oc);
        v += __shfl_xor(v, 1, 64);
        v += __shfl_xor(v, 2, 64);
        v += __shfl_xor(v, 4, 64);
        v += __shfl_xor(v, 8, 64);
        v += __shfl_xor(v, 16, 64);
        if (oc == 0) wsum[kk] = v;
    }
}

// ---- K1: MFMA conv, direct-global taps, no staging LDS.
// 2048 blocks x 128 thr (2 waves); wave = (1z, 1y, 16x) positions, all 32 oc.
__global__ __launch_bounds__(128, 4) void k_conv_mfma(
        const float* __restrict__ x, const unsigned short* __restrict__ wfrag,
        const float* __restrict__ wsum, const float* __restrict__ bias,
        float* __restrict__ Dout, float* __restrict__ Dsum) {
    __shared__ float wsl[2052];
    int tid = threadIdx.x;
    for (int i = tid; i < 2049; i += 128) wsl[i] = wsum[i];
    __syncthreads();

    int bid = blockIdx.x;
    int wid = (bid & 7) * 256 + (bid >> 3);     // XCD-chunked swizzle (2048%8==0)
    int xt = wid & 1;
    int yt = (wid >> 1) & 15;
    int zt = (wid >> 5) & 31;
    int b  = wid >> 10;
    int w = tid >> 6, lane = tid & 63;
    int col = lane & 15, g = lane >> 4;
    int pz = zt, py = yt * 2 + w, px = xt * 16 + col;

    const char* xb = (const char*)(x + (size_t)b * C * XVOL);

    // per-lane tap row byte-offsets & shift-masks (ic-invariant).
    // window: gx = gxb..gxb+3, load base gxc = clamp(gxb,0,XN-4), s = gxc-gxb.
    int gxb = 2 * px - 1;
    int gxc = min(max(gxb, 0), XN - 4);
    int s = gxc - gxb;                  // +1 at px==0, -1 at px==31, else 0
    int offb[4];
    float mc[4], ml[4], mr[4];
    #pragma unroll
    for (int h = 0; h < 2; ++h)
    #pragma unroll
    for (int rs = 0; rs < 2; ++rs) {
        int gz = 2 * pz - 1 + 2 * h + (g >> 1);
        int gy = 2 * py - 1 + (g & 1) * 2 + rs;
        bool rv = (unsigned)gz < (unsigned)XN && (unsigned)gy < (unsigned)XN;
        int gzc = min(max(gz, 0), XN - 1);
        int gyc = min(max(gy, 0), XN - 1);
        int idx = h * 2 + rs;
        offb[idx] = ((gzc * XN + gyc) * XN + gxc) * 4;
        mc[idx] = (rv && s == 0)  ? 1.f : 0.f;
        ml[idx] = (rv && s == 1)  ? 1.f : 0.f;
        mr[idx] = (rv && s == -1) ? 1.f : 0.f;
    }
    const char* wfp = (const char*)wfrag + lane * 16;

    float4v acc0 = {0.f, 0.f, 0.f, 0.f};
    float4v acc1 = {0.f, 0.f, 0.f, 0.f};
    float dp = 0.f;
    float4v tA[4], tB[4];
    short8v wA[4], wB[4];

#define LOADT(T, W, j) do {                                                  \
    const char* xp = xb + (size_t)(j) * (XVOL * 4);                          \
    _Pragma("unroll")                                                        \
    for (int i5 = 0; i5 < 4; ++i5)                                           \
        T[i5] = ((const f4u*)(xp + offb[i5]))->v;                            \
    const char* wq = wfp + (size_t)(j) * 4096;                               \
    _Pragma("unroll")                                                        \
    for (int i5 = 0; i5 < 4; ++i5)                                           \
        W[i5] = ((const s8u*)(wq + i5 * 1024))->v;                           \
} while (0)

#define COMPT(T, W, j) do {                                                  \
    _Pragma("unroll")                                                        \
    for (int h5 = 0; h5 < 2; ++h5) {                                         \
        float4v r0 = shmask(T[h5 * 2],     mc[h5 * 2],     ml[h5 * 2],     mr[h5 * 2]);     \
        float4v r1 = shmask(T[h5 * 2 + 1], mc[h5 * 2 + 1], ml[h5 * 2 + 1], mr[h5 * 2 + 1]); \
        const float4v wlo = *(const float4v*)&wsl[((j) * 2 + h5) * 32 + g * 8];     \
        const float4v whi = *(const float4v*)&wsl[((j) * 2 + h5) * 32 + g * 8 + 4]; \
        dp = fmaf(wlo[0], r0[0], dp); dp = fmaf(wlo[1], r0[1], dp);          \
        dp = fmaf(wlo[2], r0[2], dp); dp = fmaf(wlo[3], r0[3], dp);          \
        dp = fmaf(whi[0], r1[0], dp); dp = fmaf(whi[1], r1[1], dp);          \
        dp = fmaf(whi[2], r1[2], dp); dp = fmaf(whi[3], r1[3], dp);          \
        union { short8v s; unsigned u[4]; } Bv;                              \
        Bv.u[0] = pk2(r0[0], r0[1]); Bv.u[1] = pk2(r0[2], r0[3]);            \
        Bv.u[2] = pk2(r1[0], r1[1]); Bv.u[3] = pk2(r1[2], r1[3]);            \
        acc0 = __builtin_amdgcn_mfma_f32_16x16x32_bf16(W[h5 * 2],     Bv.s, acc0, 0, 0, 0); \
        acc1 = __builtin_amdgcn_mfma_f32_16x16x32_bf16(W[h5 * 2 + 1], Bv.s, acc1, 0, 0, 0); \
    }                                                                        \
} while (0)

    LOADT(tA, wA, 0);
    LOADT(tB, wB, 1);
    for (int ic = 0; ic < C - 2; ic += 2) {
        COMPT(tA, wA, ic);
        LOADT(tA, wA, ic + 2);
        COMPT(tB, wB, ic + 1);
        LOADT(tB, wB, ic + 3);
    }
    COMPT(tA, wA, C - 2);
    COMPT(tB, wB, C - 1);

#undef LOADT
#undef COMPT

    dp += __shfl_xor(dp, 16, 64);
    dp += __shfl_xor(dp, 32, 64);

    int sp = pz * (DN * DN) + py * DN + px;
    float4v b0 = *(const float4v*)&bias[g * 4];
    float4v b1 = *(const float4v*)&bias[16 + g * 4];
    #pragma unroll
    for (int r = 0; r < 4; ++r) {
        int oc0 = g * 4 + r;
        int oc1 = 16 + g * 4 + r;
        Dout[(size_t)(b * C + oc0) * DVOL + sp] = acc0[r] + b0[r];
        Dout[(size_t)(b * C + oc1) * DVOL + sp] = acc1[r] + b1[r];
    }
    if (g == 0)
        Dsum[b * DVOL + sp] = dp + wsl[2048];
}

// ---- K2: 5^3 gaussian, LDS-staged. Block = (4z x 8y x 8x), 256 blocks.
__global__ __launch_bounds__(256) void k_gauss(const float* __restrict__ Dsum,
                                               const float* __restrict__ gaus_w,
                                               float* __restrict__ filt,
                                               float* __restrict__ outg) {
    __shared__ float tg[8 * 12 * 12];   // 1152
    __shared__ float gk[125];
    int bid = blockIdx.x;
    int xt = bid & 3, yt = (bid >> 2) & 3, zt = (bid >> 4) & 7, b = bid >> 7;
    int tid = threadIdx.x;
    if (tid < 125) gk[tid] = gaus_w[tid];   // replicated kernel: [0][0] slice
    const float* Ds = Dsum + b * DVOL;
    for (int i = tid; i < 1152; i += 256) {
        int lx = i % 12; int r = i / 12; int ly = r % 12; int lz = r / 12;
        int gz = zt * 4 - 2 + lz, gy = yt * 8 - 2 + ly, gx = xt * 8 - 2 + lx;
        float v = 0.f;
        if ((unsigned)gz < DN && (unsigned)gy < DN && (unsigned)gx < DN)
            v = Ds[(gz * DN + gy) * DN + gx];
        tg[i] = v;
    }
    __syncthreads();
    int px = tid & 7, py = (tid >> 3) & 7, pz = tid >> 6;
    const float inv31 = 1.f / 31.f;
    float zb = (float)(zt * 4 + pz - 2);
    float yb = (float)(yt * 8 + py - 2);
    float xb = (float)(xt * 8 + px - 2);
    float p = 0.f, a0 = 0.f, a1 = 0.f, a2 = 0.f;
    for (int tz = 0; tz < 5; ++tz)
    for (int ty = 0; ty < 5; ++ty) {
        int base = ((pz + tz) * 12 + py + ty) * 12 + px;
        #pragma unroll
        for (int tx = 0; tx < 5; ++tx) {
            float g = gk[tz * 25 + ty * 5 + tx];
            float v = g * tg[base + tx];
            p += v;
            a0 = fmaf(v, (zb + (float)tz) * inv31, a0);
            a1 = fmaf(v, (yb + (float)ty) * inv31, a1);
            a2 = fmaf(v, (xb + (float)tx) * inv31, a2);
        }
    }
    float denom = p + 1e-6f;
    float f0 = fminf(fmaxf(a0 / denom * 2.f - 1.f, -1.f), 1.f);
    float f1 = fminf(fmaxf(a1 / denom * 2.f - 1.f, -1.f), 1.f);
    float f2 = fminf(fmaxf(a2 / denom * 2.f - 1.f, -1.f), 1.f);
    int sp = ((zt * 4 + pz) * DN + yt * 8 + py) * DN + xt * 8 + px;
    filt[(b * 3 + 0) * DVOL + sp] = f0;
    filt[(b * 3 + 1) * DVOL + sp] = f1;
    filt[(b * 3 + 2) * DVOL + sp] = f2;
    outg[(size_t)(b * DVOL + sp) * 3 + 0] = f0;
    outg[(size_t)(b * DVOL + sp) * 3 + 1] = f1;
    outg[(size_t)(b * DVOL + sp) * 3 + 2] = f2;
}

// ---- K3: trilinear grid sample. 2048 blocks x 128 thr; tile (2z,4y,16x),
// 8 channels per block. XCD chunk = one (b, channel-group), z-major.
__global__ __launch_bounds__(128, 4) void k_sample(const float* __restrict__ x,
                                                   const float* __restrict__ filt,
                                                   float* __restrict__ y) {
    int bid = blockIdx.x;
    int wid = (bid & 7) * 256 + (bid >> 3);   // 2048%8==0, bijective chunk
    int xt = wid & 1;
    int yt = (wid >> 1) & 7;
    int zt = (wid >> 4) & 15;
    int cgrp = (wid >> 8) & 3;
    int b  = wid >> 10;
    int tid = threadIdx.x;
    int px = tid & 15, py = (tid >> 4) & 3, pz = tid >> 6;
    int sp = ((zt * 2 + pz) * DN + yt * 4 + py) * DN + xt * 16 + px;
    const float* fb = filt + b * 3 * DVOL;
    float g0 = fb[sp], g1 = fb[DVOL + sp], g2 = fb[2 * DVOL + sp];

    float ix = ((g0 + 1.0f) * (float)XN - 1.0f) * 0.5f;
    float iy = ((g1 + 1.0f) * (float)XN - 1.0f) * 0.5f;
    float iz = ((g2 + 1.0f) * (float)XN - 1.0f) * 0.5f;
    float x0f = floorf(ix), y0f = floorf(iy), z0f = floorf(iz);
    float wx = ix - x0f, wyf = iy - y0f, wz = iz - z0f;
    int x0 = (int)x0f, y0i = (int)y0f, z0 = (int)z0f;

    int offs[8];
    float wts[8];
    #pragma unroll
    for (int t = 0; t < 8; ++t) {
        int dz = t >> 2, dy = (t >> 1) & 1, dx = t & 1;
        int zc = z0 + dz, yc = y0i + dy, xc = x0 + dx;
        bool valid = (unsigned)zc < (unsigned)XN && (unsigned)yc < (unsigned)XN &&
                     (unsigned)xc < (unsigned)XN;
        int zcl = min(max(zc, 0), XN - 1);
        int ycl = min(max(yc, 0), XN - 1);
        int xcl = min(max(xc, 0), XN - 1);
        offs[t] = zcl * (XN * XN) + ycl * XN + xcl;
        float w = (dz ? wz : 1.f - wz) * (dy ? wyf : 1.f - wyf) * (dx ? wx : 1.f - wx);
        wts[t] = valid ? w : 0.f;
    }

    const float* xc0 = x + (size_t)(b * C + cgrp * 8) * XVOL;
    #pragma unroll
    for (int g = 0; g < 2; ++g) {
        float t[4][8];                       // 32 loads in flight
        #pragma unroll
        for (int j = 0; j < 4; ++j) {
            const float* xb = xc0 + (size_t)(g * 4 + j) * XVOL;
            #pragma unroll
            for (int k = 0; k < 8; ++k) t[j][k] = xb[offs[k]];
        }
        #pragma unroll
        for (int j = 0; j < 4; ++j) {
            float acc = 0.f;
            #pragma unroll
            for (int k = 0; k < 8; ++k) acc = fmaf(wts[k], t[j][k], acc);
            y[(size_t)(b * C + cgrp * 8 + g * 4 + j) * DVOL + sp] = acc;
        }
    }
}

extern "C" void kernel_launch(void* const* d_in, const int* in_sizes, int n_in,
                              void* d_out, int out_size, void* d_ws, size_t ws_size,
                              hipStream_t stream) {
    const float* x      = (const float*)d_in[0];
    const float* conv_w = (const float*)d_in[1];
    const float* conv_b = (const float*)d_in[2];
    const float* gaus_w = (const float*)d_in[3];

    float* out = (float*)d_out;
    float* y_out = out;
    float* D_out = out + (size_t)2097152;
    float* g_out = out + (size_t)4194304;

    float* ws   = (float*)d_ws;
    float* Dsum = ws;                         // 65536 f
    float* filt = ws + 65536;                 // 196608 f
    float* wsum = ws + 262144;                // 2049 f (+pad)
    unsigned short* wfrag = (unsigned short*)(ws + 264256);  // 65536 u16

    k_prep<<<dim3(512), dim3(256), 0, stream>>>(conv_w, conv_b, wfrag, wsum);
    k_conv_mfma<<<dim3(2048), dim3(128), 0, stream>>>(x, wfrag, wsum, conv_b,
                                                      D_out, Dsum);
    k_gauss<<<dim3(256), dim3(256), 0, stream>>>(Dsum, gaus_w, filt, g_out);
    k_sample<<<dim3(2048), dim3(128), 0, stream>>>(x, filt, y_out);
    (void)in_sizes; (void)n_in; (void)out_size; (void)ws_size;
}

// Round 8
// 109.058 us; speedup vs baseline: 1.3702x; 1.3702x over previous
//
#include <hip/hip_runtime.h>
#include <hip/hip_bf16.h>

// ---------------------------------------------------------------------------
// Def_DownSampling, round 8.
//  * gaus_w identical per (oc,ic) => gaussian path uses channel-summed field.
//  * conv3+avgpool folded to stride-2 4^3 conv (W4), exact algebra.
//  * D via bf16 MFMA; Dsum kept fp32 (fused VALU dot) for the grid path.
//  * R8: fix R7's register-spill regression. R7's __launch_bounds__(128,4)
//    capped VGPRs at 64 while ~110 were live (ping-pong prefetch state) ->
//    ~107 MB scratch writes/dispatch. Cap removed; everything else identical.
// Outputs: y (2,32,32,32,32) | D (2,32,32,32,32) | grid-mean (2,32,32,32,3)
// ---------------------------------------------------------------------------

#define XN 64
#define DN 32
#define C  32
#define XVOL (XN * XN * XN)   // 262144
#define DVOL (DN * DN * DN)   // 32768

typedef __attribute__((ext_vector_type(8))) short short8v;
typedef __attribute__((ext_vector_type(4))) float float4v;

struct __attribute__((packed, aligned(4))) f4u { float4v v; };
struct __attribute__((packed, aligned(4))) s8u { short8v v; };

static __device__ __forceinline__ short f2bf(float f) {
    union { float f; unsigned u; } v; v.f = f;
    unsigned r = (v.u + 0x7fffu + ((v.u >> 16) & 1u)) >> 16;   // RNE
    return (short)r;
}

static __device__ __forceinline__ unsigned pk2(float a, float b) {
    __hip_bfloat162 h = __float22bfloat162_rn(float2{a, b});
    union { __hip_bfloat162 h2; unsigned u; } cv; cv.h2 = h;
    return cv.u;
}

// shifted-masked taps: out[c] = mc*ld[c] + ml*ld[c-1] + mr*ld[c+1]
static __device__ __forceinline__ float4v shmask(float4v ld, float c, float l, float r) {
    float4v o;
    o[0] = fmaf(r, ld[1], c * ld[0]);
    o[1] = fmaf(l, ld[0], fmaf(r, ld[2], c * ld[1]));
    o[2] = fmaf(l, ld[1], fmaf(r, ld[3], c * ld[2]));
    o[3] = fmaf(l, ld[2], c * ld[3]);
    return o;
}

// W4[ic][u][oc] = (1/8) sum_{s in {0,1}^3} conv_w[oc][ic][u-s]
static __device__ __forceinline__ float w4val(const float* __restrict__ conv_w,
                                              int ic, int u, int oc) {
    int uz = u >> 4, uy = (u >> 2) & 3, ux = u & 3;
    float s = 0.f;
    #pragma unroll
    for (int sz = 0; sz < 2; ++sz) {
        int tz = uz - sz; if (tz < 0 || tz > 2) continue;
        #pragma unroll
        for (int sy = 0; sy < 2; ++sy) {
            int ty = uy - sy; if (ty < 0 || ty > 2) continue;
            #pragma unroll
            for (int sx = 0; sx < 2; ++sx) {
                int tx = ux - sx; if (tx < 0 || tx > 2) continue;
                s += conv_w[(oc * C + ic) * 27 + tz * 9 + ty * 3 + tx];
            }
        }
    }
    return 0.125f * s;
}

// ---- K0: blocks 0..255 pack A-fragments (bf16) + biassum;
//          blocks 256..511 compute wsum[k] = sum_oc W4[k][oc] via shfl tree.
__global__ __launch_bounds__(256) void k_prep(const float* __restrict__ conv_w,
                                              const float* __restrict__ conv_b,
                                              unsigned short* __restrict__ wfrag,
                                              float* __restrict__ wsum) {
    int bid = blockIdx.x;
    int tid = threadIdx.x;
    if (bid < 256) {
        int i = bid * 256 + tid;                // 65536
        int e = i & 7;
        int l = (i >> 3) & 63;
        int sf = i >> 9;
        int f = sf & 1, step = sf >> 1;
        int oc = f * 16 + (l & 15);
        int k = step * 32 + ((l >> 4) * 8 + e);
        float v = w4val(conv_w, k >> 6, k & 63, oc);
        wfrag[i] = (unsigned short)f2bf(v);
        if (i == 0) {
            float s = 0.f;
            for (int o = 0; o < C; ++o) s += conv_b[o];
            wsum[2048] = s;
        }
    } else {
        int i2 = (bid - 256) * 256 + tid;       // 65536 = 2048 k x 32 oc
        int oc = tid & 31;
        int kk = i2 >> 5;
        float v = w4val(conv_w, kk >> 6, kk & 63, oc);
        v += __shfl_xor(v, 1, 64);
        v += __shfl_xor(v, 2, 64);
        v += __shfl_xor(v, 4, 64);
        v += __shfl_xor(v, 8, 64);
        v += __shfl_xor(v, 16, 64);
        if (oc == 0) wsum[kk] = v;
    }
}

// ---- K1: MFMA conv, direct-global taps, no staging LDS.
// 2048 blocks x 128 thr (2 waves); wave = (1z, 1y, 16x) positions, all 32 oc.
// NOTE: no min-waves clause — ~110 live VGPRs (ping-pong prefetch); capping
// at 64 (R7) spilled ~107 MB/dispatch to scratch.
__global__ __launch_bounds__(128) void k_conv_mfma(
        const float* __restrict__ x, const unsigned short* __restrict__ wfrag,
        const float* __restrict__ wsum, const float* __restrict__ bias,
        float* __restrict__ Dout, float* __restrict__ Dsum) {
    __shared__ float wsl[2052];
    int tid = threadIdx.x;
    for (int i = tid; i < 2049; i += 128) wsl[i] = wsum[i];
    __syncthreads();

    int bid = blockIdx.x;
    int wid = (bid & 7) * 256 + (bid >> 3);     // XCD-chunked swizzle (2048%8==0)
    int xt = wid & 1;
    int yt = (wid >> 1) & 15;
    int zt = (wid >> 5) & 31;
    int b  = wid >> 10;
    int w = tid >> 6, lane = tid & 63;
    int col = lane & 15, g = lane >> 4;
    int pz = zt, py = yt * 2 + w, px = xt * 16 + col;

    const char* xb = (const char*)(x + (size_t)b * C * XVOL);

    // per-lane tap row byte-offsets & shift-masks (ic-invariant).
    // window: gx = gxb..gxb+3, load base gxc = clamp(gxb,0,XN-4), s = gxc-gxb.
    int gxb = 2 * px - 1;
    int gxc = min(max(gxb, 0), XN - 4);
    int s = gxc - gxb;                  // +1 at px==0, -1 at px==31, else 0
    int offb[4];
    float mc[4], ml[4], mr[4];
    #pragma unroll
    for (int h = 0; h < 2; ++h)
    #pragma unroll
    for (int rs = 0; rs < 2; ++rs) {
        int gz = 2 * pz - 1 + 2 * h + (g >> 1);
        int gy = 2 * py - 1 + (g & 1) * 2 + rs;
        bool rv = (unsigned)gz < (unsigned)XN && (unsigned)gy < (unsigned)XN;
        int gzc = min(max(gz, 0), XN - 1);
        int gyc = min(max(gy, 0), XN - 1);
        int idx = h * 2 + rs;
        offb[idx] = ((gzc * XN + gyc) * XN + gxc) * 4;
        mc[idx] = (rv && s == 0)  ? 1.f : 0.f;
        ml[idx] = (rv && s == 1)  ? 1.f : 0.f;
        mr[idx] = (rv && s == -1) ? 1.f : 0.f;
    }
    const char* wfp = (const char*)wfrag + lane * 16;

    float4v acc0 = {0.f, 0.f, 0.f, 0.f};
    float4v acc1 = {0.f, 0.f, 0.f, 0.f};
    float dp = 0.f;
    float4v tA[4], tB[4];
    short8v wA[4], wB[4];

#define LOADT(T, W, j) do {                                                  \
    const char* xp = xb + (size_t)(j) * (XVOL * 4);                          \
    _Pragma("unroll")                                                        \
    for (int i5 = 0; i5 < 4; ++i5)                                           \
        T[i5] = ((const f4u*)(xp + offb[i5]))->v;                            \
    const char* wq = wfp + (size_t)(j) * 4096;                               \
    _Pragma("unroll")                                                        \
    for (int i5 = 0; i5 < 4; ++i5)                                           \
        W[i5] = ((const s8u*)(wq + i5 * 1024))->v;                           \
} while (0)

#define COMPT(T, W, j) do {                                                  \
    _Pragma("unroll")                                                        \
    for (int h5 = 0; h5 < 2; ++h5) {                                         \
        float4v r0 = shmask(T[h5 * 2],     mc[h5 * 2],     ml[h5 * 2],     mr[h5 * 2]);     \
        float4v r1 = shmask(T[h5 * 2 + 1], mc[h5 * 2 + 1], ml[h5 * 2 + 1], mr[h5 * 2 + 1]); \
        const float4v wlo = *(const float4v*)&wsl[((j) * 2 + h5) * 32 + g * 8];     \
        const float4v whi = *(const float4v*)&wsl[((j) * 2 + h5) * 32 + g * 8 + 4]; \
        dp = fmaf(wlo[0], r0[0], dp); dp = fmaf(wlo[1], r0[1], dp);          \
        dp = fmaf(wlo[2], r0[2], dp); dp = fmaf(wlo[3], r0[3], dp);          \
        dp = fmaf(whi[0], r1[0], dp); dp = fmaf(whi[1], r1[1], dp);          \
        dp = fmaf(whi[2], r1[2], dp); dp = fmaf(whi[3], r1[3], dp);          \
        union { short8v s; unsigned u[4]; } Bv;                              \
        Bv.u[0] = pk2(r0[0], r0[1]); Bv.u[1] = pk2(r0[2], r0[3]);            \
        Bv.u[2] = pk2(r1[0], r1[1]); Bv.u[3] = pk2(r1[2], r1[3]);            \
        acc0 = __builtin_amdgcn_mfma_f32_16x16x32_bf16(W[h5 * 2],     Bv.s, acc0, 0, 0, 0); \
        acc1 = __builtin_amdgcn_mfma_f32_16x16x32_bf16(W[h5 * 2 + 1], Bv.s, acc1, 0, 0, 0); \
    }                                                                        \
} while (0)

    LOADT(tA, wA, 0);
    LOADT(tB, wB, 1);
    for (int ic = 0; ic < C - 2; ic += 2) {
        COMPT(tA, wA, ic);
        LOADT(tA, wA, ic + 2);
        COMPT(tB, wB, ic + 1);
        LOADT(tB, wB, ic + 3);
    }
    COMPT(tA, wA, C - 2);
    COMPT(tB, wB, C - 1);

#undef LOADT
#undef COMPT

    dp += __shfl_xor(dp, 16, 64);
    dp += __shfl_xor(dp, 32, 64);

    int sp = pz * (DN * DN) + py * DN + px;
    float4v b0 = *(const float4v*)&bias[g * 4];
    float4v b1 = *(const float4v*)&bias[16 + g * 4];
    #pragma unroll
    for (int r = 0; r < 4; ++r) {
        int oc0 = g * 4 + r;
        int oc1 = 16 + g * 4 + r;
        Dout[(size_t)(b * C + oc0) * DVOL + sp] = acc0[r] + b0[r];
        Dout[(size_t)(b * C + oc1) * DVOL + sp] = acc1[r] + b1[r];
    }
    if (g == 0)
        Dsum[b * DVOL + sp] = dp + wsl[2048];
}

// ---- K2: 5^3 gaussian, LDS-staged. Block = (4z x 8y x 8x), 256 blocks.
__global__ __launch_bounds__(256) void k_gauss(const float* __restrict__ Dsum,
                                               const float* __restrict__ gaus_w,
                                               float* __restrict__ filt,
                                               float* __restrict__ outg) {
    __shared__ float tg[8 * 12 * 12];   // 1152
    __shared__ float gk[125];
    int bid = blockIdx.x;
    int xt = bid & 3, yt = (bid >> 2) & 3, zt = (bid >> 4) & 7, b = bid >> 7;
    int tid = threadIdx.x;
    if (tid < 125) gk[tid] = gaus_w[tid];   // replicated kernel: [0][0] slice
    const float* Ds = Dsum + b * DVOL;
    for (int i = tid; i < 1152; i += 256) {
        int lx = i % 12; int r = i / 12; int ly = r % 12; int lz = r / 12;
        int gz = zt * 4 - 2 + lz, gy = yt * 8 - 2 + ly, gx = xt * 8 - 2 + lx;
        float v = 0.f;
        if ((unsigned)gz < DN && (unsigned)gy < DN && (unsigned)gx < DN)
            v = Ds[(gz * DN + gy) * DN + gx];
        tg[i] = v;
    }
    __syncthreads();
    int px = tid & 7, py = (tid >> 3) & 7, pz = tid >> 6;
    const float inv31 = 1.f / 31.f;
    float zb = (float)(zt * 4 + pz - 2);
    float yb = (float)(yt * 8 + py - 2);
    float xb = (float)(xt * 8 + px - 2);
    float p = 0.f, a0 = 0.f, a1 = 0.f, a2 = 0.f;
    for (int tz = 0; tz < 5; ++tz)
    for (int ty = 0; ty < 5; ++ty) {
        int base = ((pz + tz) * 12 + py + ty) * 12 + px;
        #pragma unroll
        for (int tx = 0; tx < 5; ++tx) {
            float g = gk[tz * 25 + ty * 5 + tx];
            float v = g * tg[base + tx];
            p += v;
            a0 = fmaf(v, (zb + (float)tz) * inv31, a0);
            a1 = fmaf(v, (yb + (float)ty) * inv31, a1);
            a2 = fmaf(v, (xb + (float)tx) * inv31, a2);
        }
    }
    float denom = p + 1e-6f;
    float f0 = fminf(fmaxf(a0 / denom * 2.f - 1.f, -1.f), 1.f);
    float f1 = fminf(fmaxf(a1 / denom * 2.f - 1.f, -1.f), 1.f);
    float f2 = fminf(fmaxf(a2 / denom * 2.f - 1.f, -1.f), 1.f);
    int sp = ((zt * 4 + pz) * DN + yt * 8 + py) * DN + xt * 8 + px;
    filt[(b * 3 + 0) * DVOL + sp] = f0;
    filt[(b * 3 + 1) * DVOL + sp] = f1;
    filt[(b * 3 + 2) * DVOL + sp] = f2;
    outg[(size_t)(b * DVOL + sp) * 3 + 0] = f0;
    outg[(size_t)(b * DVOL + sp) * 3 + 1] = f1;
    outg[(size_t)(b * DVOL + sp) * 3 + 2] = f2;
}

// ---- K3: trilinear grid sample. 2048 blocks x 128 thr; tile (2z,4y,16x),
// 8 channels per block. XCD chunk = one (b, channel-group), z-major.
__global__ __launch_bounds__(128, 4) void k_sample(const float* __restrict__ x,
                                                   const float* __restrict__ filt,
                                                   float* __restrict__ y) {
    int bid = blockIdx.x;
    int wid = (bid & 7) * 256 + (bid >> 3);   // 2048%8==0, bijective chunk
    int xt = wid & 1;
    int yt = (wid >> 1) & 7;
    int zt = (wid >> 4) & 15;
    int cgrp = (wid >> 8) & 3;
    int b  = wid >> 10;
    int tid = threadIdx.x;
    int px = tid & 15, py = (tid >> 4) & 3, pz = tid >> 6;
    int sp = ((zt * 2 + pz) * DN + yt * 4 + py) * DN + xt * 16 + px;
    const float* fb = filt + b * 3 * DVOL;
    float g0 = fb[sp], g1 = fb[DVOL + sp], g2 = fb[2 * DVOL + sp];

    float ix = ((g0 + 1.0f) * (float)XN - 1.0f) * 0.5f;
    float iy = ((g1 + 1.0f) * (float)XN - 1.0f) * 0.5f;
    float iz = ((g2 + 1.0f) * (float)XN - 1.0f) * 0.5f;
    float x0f = floorf(ix), y0f = floorf(iy), z0f = floorf(iz);
    float wx = ix - x0f, wyf = iy - y0f, wz = iz - z0f;
    int x0 = (int)x0f, y0i = (int)y0f, z0 = (int)z0f;

    int offs[8];
    float wts[8];
    #pragma unroll
    for (int t = 0; t < 8; ++t) {
        int dz = t >> 2, dy = (t >> 1) & 1, dx = t & 1;
        int zc = z0 + dz, yc = y0i + dy, xc = x0 + dx;
        bool valid = (unsigned)zc < (unsigned)XN && (unsigned)yc < (unsigned)XN &&
                     (unsigned)xc < (unsigned)XN;
        int zcl = min(max(zc, 0), XN - 1);
        int ycl = min(max(yc, 0), XN - 1);
        int xcl = min(max(xc, 0), XN - 1);
        offs[t] = zcl * (XN * XN) + ycl * XN + xcl;
        float w = (dz ? wz : 1.f - wz) * (dy ? wyf : 1.f - wyf) * (dx ? wx : 1.f - wx);
        wts[t] = valid ? w : 0.f;
    }

    const float* xc0 = x + (size_t)(b * C + cgrp * 8) * XVOL;
    #pragma unroll
    for (int g = 0; g < 2; ++g) {
        float t[4][8];                       // 32 loads in flight
        #pragma unroll
        for (int j = 0; j < 4; ++j) {
            const float* xb = xc0 + (size_t)(g * 4 + j) * XVOL;
            #pragma unroll
            for (int k = 0; k < 8; ++k) t[j][k] = xb[offs[k]];
        }
        #pragma unroll
        for (int j = 0; j < 4; ++j) {
            float acc = 0.f;
            #pragma unroll
            for (int k = 0; k < 8; ++k) acc = fmaf(wts[k], t[j][k], acc);
            y[(size_t)(b * C + cgrp * 8 + g * 4 + j) * DVOL + sp] = acc;
        }
    }
}

extern "C" void kernel_launch(void* const* d_in, const int* in_sizes, int n_in,
                              void* d_out, int out_size, void* d_ws, size_t ws_size,
                              hipStream_t stream) {
    const float* x      = (const float*)d_in[0];
    const float* conv_w = (const float*)d_in[1];
    const float* conv_b = (const float*)d_in[2];
    const float* gaus_w = (const float*)d_in[3];

    float* out = (float*)d_out;
    float* y_out = out;
    float* D_out = out + (size_t)2097152;
    float* g_out = out + (size_t)4194304;

    float* ws   = (float*)d_ws;
    float* Dsum = ws;                         // 65536 f
    float* filt = ws + 65536;                 // 196608 f
    float* wsum = ws + 262144;                // 2049 f (+pad)
    unsigned short* wfrag = (unsigned short*)(ws + 264256);  // 65536 u16

    k_prep<<<dim3(512), dim3(256), 0, stream>>>(conv_w, conv_b, wfrag, wsum);
    k_conv_mfma<<<dim3(2048), dim3(128), 0, stream>>>(x, wfrag, wsum, conv_b,
                                                      D_out, Dsum);
    k_gauss<<<dim3(256), dim3(256), 0, stream>>>(Dsum, gaus_w, filt, g_out);
    k_sample<<<dim3(2048), dim3(128), 0, stream>>>(x, filt, y_out);
    (void)in_sizes; (void)n_in; (void)out_size; (void)ws_size;
}

// Round 9
// 108.149 us; speedup vs baseline: 1.3817x; 1.0084x over previous
//
#include <hip/hip_runtime.h>
#include <hip/hip_bf16.h>

// ---------------------------------------------------------------------------
// Def_DownSampling, round 9.
//  * gaus_w identical per (oc,ic) => gaussian path uses channel-summed field.
//  * conv3+avgpool folded to stride-2 4^3 conv (W4), exact algebra.
//  * D via bf16 MFMA; Dsum kept fp32 (fused pk-fma dot) for the grid path.
//  * R9: conv waves own 32 positions (full x-row, 2 MFMA tiles) -> weight
//    L2 traffic halved; 64-thr 1-wave blocks (grid 2048, 8/CU); specialized
//    boundary shifts shmL/shmR (4 VALU/row); float4v dp (packed fma).
// Outputs: y (2,32,32,32,32) | D (2,32,32,32,32) | grid-mean (2,32,32,32,3)
// ---------------------------------------------------------------------------

#define XN 64
#define DN 32
#define C  32
#define XVOL (XN * XN * XN)   // 262144
#define DVOL (DN * DN * DN)   // 32768

typedef __attribute__((ext_vector_type(8))) short short8v;
typedef __attribute__((ext_vector_type(4))) float float4v;

struct __attribute__((packed, aligned(4))) f4u { float4v v; };
struct __attribute__((packed, aligned(4))) s8u { short8v v; };

static __device__ __forceinline__ short f2bf(float f) {
    union { float f; unsigned u; } v; v.f = f;
    unsigned r = (v.u + 0x7fffu + ((v.u >> 16) & 1u)) >> 16;   // RNE
    return (short)r;
}

static __device__ __forceinline__ unsigned pk2(float a, float b) {
    __hip_bfloat162 h = __float22bfloat162_rn(float2{a, b});
    union { __hip_bfloat162 h2; unsigned u; } cv; cv.h2 = h;
    return cv.u;
}

// tile0 boundary (only possible shift: window moved right by 1 at px==0):
// out = [c*ld0, c*ld1+l*ld0, c*ld2+l*ld1, c*ld3+l*ld2]
static __device__ __forceinline__ float4v shmL(float4v ld, float c, float l) {
    float4v o;
    o[0] = c * ld[0];
    o[1] = fmaf(l, ld[0], c * ld[1]);
    o[2] = fmaf(l, ld[1], c * ld[2]);
    o[3] = fmaf(l, ld[2], c * ld[3]);
    return o;
}
// tile1 boundary (only possible shift: window moved left by 1 at px==31):
// out = [c*ld0+r*ld1, c*ld1+r*ld2, c*ld2+r*ld3, c*ld3]
static __device__ __forceinline__ float4v shmR(float4v ld, float c, float r) {
    float4v o;
    o[0] = fmaf(r, ld[1], c * ld[0]);
    o[1] = fmaf(r, ld[2], c * ld[1]);
    o[2] = fmaf(r, ld[3], c * ld[2]);
    o[3] = c * ld[3];
    return o;
}

// W4[ic][u][oc] = (1/8) sum_{s in {0,1}^3} conv_w[oc][ic][u-s]
static __device__ __forceinline__ float w4val(const float* __restrict__ conv_w,
                                              int ic, int u, int oc) {
    int uz = u >> 4, uy = (u >> 2) & 3, ux = u & 3;
    float s = 0.f;
    #pragma unroll
    for (int sz = 0; sz < 2; ++sz) {
        int tz = uz - sz; if (tz < 0 || tz > 2) continue;
        #pragma unroll
        for (int sy = 0; sy < 2; ++sy) {
            int ty = uy - sy; if (ty < 0 || ty > 2) continue;
            #pragma unroll
            for (int sx = 0; sx < 2; ++sx) {
                int tx = ux - sx; if (tx < 0 || tx > 2) continue;
                s += conv_w[(oc * C + ic) * 27 + tz * 9 + ty * 3 + tx];
            }
        }
    }
    return 0.125f * s;
}

// ---- K0: blocks 0..255 pack A-fragments (bf16) + biassum;
//          blocks 256..511 compute wsum[k] = sum_oc W4[k][oc] via shfl tree.
__global__ __launch_bounds__(256) void k_prep(const float* __restrict__ conv_w,
                                              const float* __restrict__ conv_b,
                                              unsigned short* __restrict__ wfrag,
                                              float* __restrict__ wsum) {
    int bid = blockIdx.x;
    int tid = threadIdx.x;
    if (bid < 256) {
        int i = bid * 256 + tid;                // 65536
        int e = i & 7;
        int l = (i >> 3) & 63;
        int sf = i >> 9;
        int f = sf & 1, step = sf >> 1;
        int oc = f * 16 + (l & 15);
        int k = step * 32 + ((l >> 4) * 8 + e);
        float v = w4val(conv_w, k >> 6, k & 63, oc);
        wfrag[i] = (unsigned short)f2bf(v);
        if (i == 0) {
            float s = 0.f;
            for (int o = 0; o < C; ++o) s += conv_b[o];
            wsum[2048] = s;
        }
    } else {
        int i2 = (bid - 256) * 256 + tid;       // 65536 = 2048 k x 32 oc
        int oc = tid & 31;
        int kk = i2 >> 5;
        float v = w4val(conv_w, kk >> 6, kk & 63, oc);
        v += __shfl_xor(v, 1, 64);
        v += __shfl_xor(v, 2, 64);
        v += __shfl_xor(v, 4, 64);
        v += __shfl_xor(v, 8, 64);
        v += __shfl_xor(v, 16, 64);
        if (oc == 0) wsum[kk] = v;
    }
}

// ---- K1: MFMA conv. 2048 blocks x 64 thr (1 wave).
// Wave = (1z, 1y, 32x) output positions (two 16-col MFMA tiles), all 32 oc.
__global__ __launch_bounds__(64) void k_conv_mfma(
        const float* __restrict__ x, const unsigned short* __restrict__ wfrag,
        const float* __restrict__ wsum, const float* __restrict__ bias,
        float* __restrict__ Dout, float* __restrict__ Dsum) {
    __shared__ float wsl[2112];
    int tid = threadIdx.x;                       // 0..63
    for (int i = tid; i < 513; i += 64)          // 2052 floats, region has 2112
        *(float4v*)&wsl[i * 4] = *(const float4v*)&wsum[i * 4];
    __syncthreads();

    int bid = blockIdx.x;
    int wid = (bid & 7) * 256 + (bid >> 3);      // XCD-chunked swizzle (2048%8==0)
    int py = wid & 31;
    int pz = (wid >> 5) & 31;
    int b  = wid >> 10;
    int lane = tid, col = lane & 15, g = lane >> 4;

    const char* xb = (const char*)(x + (size_t)b * C * XVOL);

    // per-lane row byte-offsets & boundary coeffs (ic-invariant)
    // tile0: px=col (shift only at col==0); tile1: px=col+16 (shift at col==15)
    int gxb0 = 2 * col - 1;
    int gxc0 = max(gxb0, 0);
    int gxb1 = 2 * (col + 16) - 1;
    int gxc1 = min(gxb1, XN - 4);
    int offb[8];
    float cfc[8], cfs[8];
    #pragma unroll
    for (int h = 0; h < 2; ++h)
    #pragma unroll
    for (int rs = 0; rs < 2; ++rs) {
        int idx = h * 2 + rs;
        int gz = 2 * pz - 1 + 2 * h + (g >> 1);
        int gy = 2 * py - 1 + (g & 1) * 2 + rs;
        bool rv = (unsigned)gz < (unsigned)XN && (unsigned)gy < (unsigned)XN;
        int gzc = min(max(gz, 0), XN - 1);
        int gyc = min(max(gy, 0), XN - 1);
        int rowb = (gzc * XN + gyc) * (XN * 4);
        offb[idx]     = rowb + gxc0 * 4;
        offb[4 + idx] = rowb + gxc1 * 4;
        cfc[idx]     = (rv && col != 0)  ? 1.f : 0.f;
        cfs[idx]     = (rv && col == 0)  ? 1.f : 0.f;
        cfc[4 + idx] = (rv && col != 15) ? 1.f : 0.f;
        cfs[4 + idx] = (rv && col == 15) ? 1.f : 0.f;
    }
    const char* wfp = (const char*)wfrag + lane * 16;

    float4v acc00 = {0.f, 0.f, 0.f, 0.f};   // tile0, oc 0-15
    float4v acc01 = {0.f, 0.f, 0.f, 0.f};   // tile0, oc 16-31
    float4v acc10 = {0.f, 0.f, 0.f, 0.f};   // tile1, oc 0-15
    float4v acc11 = {0.f, 0.f, 0.f, 0.f};   // tile1, oc 16-31
    float4v dp0 = {0.f, 0.f, 0.f, 0.f};
    float4v dp1 = {0.f, 0.f, 0.f, 0.f};
    float4v tA[8], tB[8];
    short8v wA[4], wB[4];

#define LOADT(T, W, j) do {                                                  \
    const char* xp = xb + (size_t)(j) * (XVOL * 4);                          \
    _Pragma("unroll")                                                        \
    for (int i5 = 0; i5 < 8; ++i5)                                           \
        T[i5] = ((const f4u*)(xp + offb[i5]))->v;                            \
    const char* wq = wfp + (size_t)(j) * 4096;                               \
    _Pragma("unroll")                                                        \
    for (int i5 = 0; i5 < 4; ++i5)                                           \
        W[i5] = ((const s8u*)(wq + i5 * 1024))->v;                           \
} while (0)

#define COMPT(T, W, j) do {                                                  \
    _Pragma("unroll")                                                        \
    for (int h5 = 0; h5 < 2; ++h5) {                                         \
        float4v r0a = shmL(T[h5 * 2],     cfc[h5 * 2],     cfs[h5 * 2]);     \
        float4v r1a = shmL(T[h5 * 2 + 1], cfc[h5 * 2 + 1], cfs[h5 * 2 + 1]); \
        float4v r0b = shmR(T[4 + h5 * 2],     cfc[4 + h5 * 2],     cfs[4 + h5 * 2]);     \
        float4v r1b = shmR(T[4 + h5 * 2 + 1], cfc[4 + h5 * 2 + 1], cfs[4 + h5 * 2 + 1]); \
        const float4v wlo = *(const float4v*)&wsl[((j) * 2 + h5) * 32 + g * 8];     \
        const float4v whi = *(const float4v*)&wsl[((j) * 2 + h5) * 32 + g * 8 + 4]; \
        dp0 += wlo * r0a; dp0 += whi * r1a;                                  \
        dp1 += wlo * r0b; dp1 += whi * r1b;                                  \
        union { short8v s; unsigned u[4]; } Ba, Bb;                          \
        Ba.u[0] = pk2(r0a[0], r0a[1]); Ba.u[1] = pk2(r0a[2], r0a[3]);        \
        Ba.u[2] = pk2(r1a[0], r1a[1]); Ba.u[3] = pk2(r1a[2], r1a[3]);        \
        Bb.u[0] = pk2(r0b[0], r0b[1]); Bb.u[1] = pk2(r0b[2], r0b[3]);        \
        Bb.u[2] = pk2(r1b[0], r1b[1]); Bb.u[3] = pk2(r1b[2], r1b[3]);        \
        acc00 = __builtin_amdgcn_mfma_f32_16x16x32_bf16(W[h5 * 2],     Ba.s, acc00, 0, 0, 0); \
        acc01 = __builtin_amdgcn_mfma_f32_16x16x32_bf16(W[h5 * 2 + 1], Ba.s, acc01, 0, 0, 0); \
        acc10 = __builtin_amdgcn_mfma_f32_16x16x32_bf16(W[h5 * 2],     Bb.s, acc10, 0, 0, 0); \
        acc11 = __builtin_amdgcn_mfma_f32_16x16x32_bf16(W[h5 * 2 + 1], Bb.s, acc11, 0, 0, 0); \
    }                                                                        \
} while (0)

    LOADT(tA, wA, 0);
    LOADT(tB, wB, 1);
    for (int ic = 0; ic < C - 2; ic += 2) {
        COMPT(tA, wA, ic);
        LOADT(tA, wA, ic + 2);
        COMPT(tB, wB, ic + 1);
        LOADT(tB, wB, ic + 3);
    }
    COMPT(tA, wA, C - 2);
    COMPT(tB, wB, C - 1);

#undef LOADT
#undef COMPT

    float d0 = (dp0[0] + dp0[1]) + (dp0[2] + dp0[3]);
    float d1 = (dp1[0] + dp1[1]) + (dp1[2] + dp1[3]);
    d0 += __shfl_xor(d0, 16, 64);
    d0 += __shfl_xor(d0, 32, 64);
    d1 += __shfl_xor(d1, 16, 64);
    d1 += __shfl_xor(d1, 32, 64);

    int sp0 = pz * (DN * DN) + py * DN + col;
    int sp1 = sp0 + 16;
    float4v b0 = *(const float4v*)&bias[g * 4];
    float4v b1 = *(const float4v*)&bias[16 + g * 4];
    #pragma unroll
    for (int r = 0; r < 4; ++r) {
        int oc0 = g * 4 + r;
        int oc1 = 16 + g * 4 + r;
        Dout[(size_t)(b * C + oc0) * DVOL + sp0] = acc00[r] + b0[r];
        Dout[(size_t)(b * C + oc1) * DVOL + sp0] = acc01[r] + b1[r];
        Dout[(size_t)(b * C + oc0) * DVOL + sp1] = acc10[r] + b0[r];
        Dout[(size_t)(b * C + oc1) * DVOL + sp1] = acc11[r] + b1[r];
    }
    if (g == 0) {
        Dsum[b * DVOL + sp0] = d0 + wsl[2048];
        Dsum[b * DVOL + sp1] = d1 + wsl[2048];
    }
}

// ---- K2: 5^3 gaussian, LDS-staged. Block = (4z x 8y x 8x), 256 blocks.
__global__ __launch_bounds__(256) void k_gauss(const float* __restrict__ Dsum,
                                               const float* __restrict__ gaus_w,
                                               float* __restrict__ filt,
                                               float* __restrict__ outg) {
    __shared__ float tg[8 * 12 * 12];   // 1152
    __shared__ float gk[125];
    int bid = blockIdx.x;
    int xt = bid & 3, yt = (bid >> 2) & 3, zt = (bid >> 4) & 7, b = bid >> 7;
    int tid = threadIdx.x;
    if (tid < 125) gk[tid] = gaus_w[tid];   // replicated kernel: [0][0] slice
    const float* Ds = Dsum + b * DVOL;
    for (int i = tid; i < 1152; i += 256) {
        int lx = i % 12; int r = i / 12; int ly = r % 12; int lz = r / 12;
        int gz = zt * 4 - 2 + lz, gy = yt * 8 - 2 + ly, gx = xt * 8 - 2 + lx;
        float v = 0.f;
        if ((unsigned)gz < DN && (unsigned)gy < DN && (unsigned)gx < DN)
            v = Ds[(gz * DN + gy) * DN + gx];
        tg[i] = v;
    }
    __syncthreads();
    int px = tid & 7, py = (tid >> 3) & 7, pz = tid >> 6;
    const float inv31 = 1.f / 31.f;
    float zb = (float)(zt * 4 + pz - 2);
    float yb = (float)(yt * 8 + py - 2);
    float xb = (float)(xt * 8 + px - 2);
    float p = 0.f, a0 = 0.f, a1 = 0.f, a2 = 0.f;
    for (int tz = 0; tz < 5; ++tz)
    for (int ty = 0; ty < 5; ++ty) {
        int base = ((pz + tz) * 12 + py + ty) * 12 + px;
        #pragma unroll
        for (int tx = 0; tx < 5; ++tx) {
            float g = gk[tz * 25 + ty * 5 + tx];
            float v = g * tg[base + tx];
            p += v;
            a0 = fmaf(v, (zb + (float)tz) * inv31, a0);
            a1 = fmaf(v, (yb + (float)ty) * inv31, a1);
            a2 = fmaf(v, (xb + (float)tx) * inv31, a2);
        }
    }
    float denom = p + 1e-6f;
    float f0 = fminf(fmaxf(a0 / denom * 2.f - 1.f, -1.f), 1.f);
    float f1 = fminf(fmaxf(a1 / denom * 2.f - 1.f, -1.f), 1.f);
    float f2 = fminf(fmaxf(a2 / denom * 2.f - 1.f, -1.f), 1.f);
    int sp = ((zt * 4 + pz) * DN + yt * 8 + py) * DN + xt * 8 + px;
    filt[(b * 3 + 0) * DVOL + sp] = f0;
    filt[(b * 3 + 1) * DVOL + sp] = f1;
    filt[(b * 3 + 2) * DVOL + sp] = f2;
    outg[(size_t)(b * DVOL + sp) * 3 + 0] = f0;
    outg[(size_t)(b * DVOL + sp) * 3 + 1] = f1;
    outg[(size_t)(b * DVOL + sp) * 3 + 2] = f2;
}

// ---- K3: trilinear grid sample. 2048 blocks x 128 thr; tile (2z,4y,16x),
// 8 channels per block. XCD chunk = one (b, channel-group), z-major.
__global__ __launch_bounds__(128, 4) void k_sample(const float* __restrict__ x,
                                                   const float* __restrict__ filt,
                                                   float* __restrict__ y) {
    int bid = blockIdx.x;
    int wid = (bid & 7) * 256 + (bid >> 3);   // 2048%8==0, bijective chunk
    int xt = wid & 1;
    int yt = (wid >> 1) & 7;
    int zt = (wid >> 4) & 15;
    int cgrp = (wid >> 8) & 3;
    int b  = wid >> 10;
    int tid = threadIdx.x;
    int px = tid & 15, py = (tid >> 4) & 3, pz = tid >> 6;
    int sp = ((zt * 2 + pz) * DN + yt * 4 + py) * DN + xt * 16 + px;
    const float* fb = filt + b * 3 * DVOL;
    float g0 = fb[sp], g1 = fb[DVOL + sp], g2 = fb[2 * DVOL + sp];

    float ix = ((g0 + 1.0f) * (float)XN - 1.0f) * 0.5f;
    float iy = ((g1 + 1.0f) * (float)XN - 1.0f) * 0.5f;
    float iz = ((g2 + 1.0f) * (float)XN - 1.0f) * 0.5f;
    float x0f = floorf(ix), y0f = floorf(iy), z0f = floorf(iz);
    float wx = ix - x0f, wyf = iy - y0f, wz = iz - z0f;
    int x0 = (int)x0f, y0i = (int)y0f, z0 = (int)z0f;

    int offs[8];
    float wts[8];
    #pragma unroll
    for (int t = 0; t < 8; ++t) {
        int dz = t >> 2, dy = (t >> 1) & 1, dx = t & 1;
        int zc = z0 + dz, yc = y0i + dy, xc = x0 + dx;
        bool valid = (unsigned)zc < (unsigned)XN && (unsigned)yc < (unsigned)XN &&
                     (unsigned)xc < (unsigned)XN;
        int zcl = min(max(zc, 0), XN - 1);
        int ycl = min(max(yc, 0), XN - 1);
        int xcl = min(max(xc, 0), XN - 1);
        offs[t] = zcl * (XN * XN) + ycl * XN + xcl;
        float w = (dz ? wz : 1.f - wz) * (dy ? wyf : 1.f - wyf) * (dx ? wx : 1.f - wx);
        wts[t] = valid ? w : 0.f;
    }

    const float* xc0 = x + (size_t)(b * C + cgrp * 8) * XVOL;
    #pragma unroll
    for (int g = 0; g < 2; ++g) {
        float t[4][8];                       // 32 loads in flight
        #pragma unroll
        for (int j = 0; j < 4; ++j) {
            const float* xb = xc0 + (size_t)(g * 4 + j) * XVOL;
            #pragma unroll
            for (int k = 0; k < 8; ++k) t[j][k] = xb[offs[k]];
        }
        #pragma unroll
        for (int j = 0; j < 4; ++j) {
            float acc = 0.f;
            #pragma unroll
            for (int k = 0; k < 8; ++k) acc = fmaf(wts[k], t[j][k], acc);
            y[(size_t)(b * C + cgrp * 8 + g * 4 + j) * DVOL + sp] = acc;
        }
    }
}

extern "C" void kernel_launch(void* const* d_in, const int* in_sizes, int n_in,
                              void* d_out, int out_size, void* d_ws, size_t ws_size,
                              hipStream_t stream) {
    const float* x      = (const float*)d_in[0];
    const float* conv_w = (const float*)d_in[1];
    const float* conv_b = (const float*)d_in[2];
    const float* gaus_w = (const float*)d_in[3];

    float* out = (float*)d_out;
    float* y_out = out;
    float* D_out = out + (size_t)2097152;
    float* g_out = out + (size_t)4194304;

    float* ws   = (float*)d_ws;
    float* Dsum = ws;                         // 65536 f
    float* filt = ws + 65536;                 // 196608 f
    float* wsum = ws + 262144;                // 2049 f (+pad to 2112)
    unsigned short* wfrag = (unsigned short*)(ws + 264256);  // 65536 u16

    k_prep<<<dim3(512), dim3(256), 0, stream>>>(conv_w, conv_b, wfrag, wsum);
    k_conv_mfma<<<dim3(2048), dim3(64), 0, stream>>>(x, wfrag, wsum, conv_b,
                                                     D_out, Dsum);
    k_gauss<<<dim3(256), dim3(256), 0, stream>>>(Dsum, gaus_w, filt, g_out);
    k_sample<<<dim3(2048), dim3(128), 0, stream>>>(x, filt, y_out);
    (void)in_sizes; (void)n_in; (void)out_size; (void)ws_size;
}

// Round 10
// 107.843 us; speedup vs baseline: 1.3856x; 1.0028x over previous
//
#include <hip/hip_runtime.h>
#include <hip/hip_bf16.h>

// ---------------------------------------------------------------------------
// Def_DownSampling, round 10.
//  * gaus_w identical per (oc,ic) => gaussian path uses channel-summed field.
//  * conv3+avgpool folded to stride-2 4^3 conv (W4), exact algebra.
//  * D via bf16 MFMA; Dsum kept fp32 (fused VALU dot) for the grid path.
//  * R10: conv = R8 inner structure (16-pos wave, 4 taps+4 weights/ic,
//    shmask boundary) but 4096 x 1-wave blocks -> 16 distinct tile streams
//    per CU (R8 vs R9 A/B showed correlated waves add no miss parallelism;
//    conv is L3-latency bound at ~8 miss-streams/CU).
// Outputs: y (2,32,32,32,32) | D (2,32,32,32,32) | grid-mean (2,32,32,32,3)
// ---------------------------------------------------------------------------

#define XN 64
#define DN 32
#define C  32
#define XVOL (XN * XN * XN)   // 262144
#define DVOL (DN * DN * DN)   // 32768

typedef __attribute__((ext_vector_type(8))) short short8v;
typedef __attribute__((ext_vector_type(4))) float float4v;

struct __attribute__((packed, aligned(4))) f4u { float4v v; };
struct __attribute__((packed, aligned(4))) s8u { short8v v; };

static __device__ __forceinline__ short f2bf(float f) {
    union { float f; unsigned u; } v; v.f = f;
    unsigned r = (v.u + 0x7fffu + ((v.u >> 16) & 1u)) >> 16;   // RNE
    return (short)r;
}

static __device__ __forceinline__ unsigned pk2(float a, float b) {
    __hip_bfloat162 h = __float22bfloat162_rn(float2{a, b});
    union { __hip_bfloat162 h2; unsigned u; } cv; cv.h2 = h;
    return cv.u;
}

// shifted-masked taps: out[c] = mc*ld[c] + ml*ld[c-1] + mr*ld[c+1]
static __device__ __forceinline__ float4v shmask(float4v ld, float c, float l, float r) {
    float4v o;
    o[0] = fmaf(r, ld[1], c * ld[0]);
    o[1] = fmaf(l, ld[0], fmaf(r, ld[2], c * ld[1]));
    o[2] = fmaf(l, ld[1], fmaf(r, ld[3], c * ld[2]));
    o[3] = fmaf(l, ld[2], c * ld[3]);
    return o;
}

// W4[ic][u][oc] = (1/8) sum_{s in {0,1}^3} conv_w[oc][ic][u-s]
static __device__ __forceinline__ float w4val(const float* __restrict__ conv_w,
                                              int ic, int u, int oc) {
    int uz = u >> 4, uy = (u >> 2) & 3, ux = u & 3;
    float s = 0.f;
    #pragma unroll
    for (int sz = 0; sz < 2; ++sz) {
        int tz = uz - sz; if (tz < 0 || tz > 2) continue;
        #pragma unroll
        for (int sy = 0; sy < 2; ++sy) {
            int ty = uy - sy; if (ty < 0 || ty > 2) continue;
            #pragma unroll
            for (int sx = 0; sx < 2; ++sx) {
                int tx = ux - sx; if (tx < 0 || tx > 2) continue;
                s += conv_w[(oc * C + ic) * 27 + tz * 9 + ty * 3 + tx];
            }
        }
    }
    return 0.125f * s;
}

// ---- K0: blocks 0..255 pack A-fragments (bf16) + biassum;
//          blocks 256..511 compute wsum[k] = sum_oc W4[k][oc] via shfl tree.
__global__ __launch_bounds__(256) void k_prep(const float* __restrict__ conv_w,
                                              const float* __restrict__ conv_b,
                                              unsigned short* __restrict__ wfrag,
                                              float* __restrict__ wsum) {
    int bid = blockIdx.x;
    int tid = threadIdx.x;
    if (bid < 256) {
        int i = bid * 256 + tid;                // 65536
        int e = i & 7;
        int l = (i >> 3) & 63;
        int sf = i >> 9;
        int f = sf & 1, step = sf >> 1;
        int oc = f * 16 + (l & 15);
        int k = step * 32 + ((l >> 4) * 8 + e);
        float v = w4val(conv_w, k >> 6, k & 63, oc);
        wfrag[i] = (unsigned short)f2bf(v);
        if (i == 0) {
            float s = 0.f;
            for (int o = 0; o < C; ++o) s += conv_b[o];
            wsum[2048] = s;
        }
    } else {
        int i2 = (bid - 256) * 256 + tid;       // 65536 = 2048 k x 32 oc
        int oc = tid & 31;
        int kk = i2 >> 5;
        float v = w4val(conv_w, kk >> 6, kk & 63, oc);
        v += __shfl_xor(v, 1, 64);
        v += __shfl_xor(v, 2, 64);
        v += __shfl_xor(v, 4, 64);
        v += __shfl_xor(v, 8, 64);
        v += __shfl_xor(v, 16, 64);
        if (oc == 0) wsum[kk] = v;
    }
}

// ---- K1: MFMA conv. 4096 blocks x 64 thr (1 wave each).
// Wave = (1z, 1y, 16x) output positions, all 32 oc. 16 blocks/CU ->
// 16 distinct L3-miss streams per CU.
__global__ __launch_bounds__(64) void k_conv_mfma(
        const float* __restrict__ x, const unsigned short* __restrict__ wfrag,
        const float* __restrict__ wsum, const float* __restrict__ bias,
        float* __restrict__ Dout, float* __restrict__ Dsum) {
    __shared__ float wsl[2112];
    int tid = threadIdx.x;                       // 0..63
    for (int i = tid; i < 513; i += 64)
        *(float4v*)&wsl[i * 4] = *(const float4v*)&wsum[i * 4];
    __syncthreads();

    int bid = blockIdx.x;
    int wid = (bid & 7) * 512 + (bid >> 3);      // XCD-chunked swizzle (4096%8==0)
    int xt = wid & 1;
    int py = (wid >> 1) & 31;
    int pz = (wid >> 6) & 31;
    int b  = wid >> 11;
    int lane = tid, col = lane & 15, g = lane >> 4;
    int px = xt * 16 + col;

    const char* xb = (const char*)(x + (size_t)b * C * XVOL);

    // per-lane tap row byte-offsets & shift-masks (ic-invariant)
    int gxb = 2 * px - 1;
    int gxc = min(max(gxb, 0), XN - 4);
    int s = gxc - gxb;                  // +1 at px==0, -1 at px==31, else 0
    int offb[4];
    float mc[4], ml[4], mr[4];
    #pragma unroll
    for (int h = 0; h < 2; ++h)
    #pragma unroll
    for (int rs = 0; rs < 2; ++rs) {
        int gz = 2 * pz - 1 + 2 * h + (g >> 1);
        int gy = 2 * py - 1 + (g & 1) * 2 + rs;
        bool rv = (unsigned)gz < (unsigned)XN && (unsigned)gy < (unsigned)XN;
        int gzc = min(max(gz, 0), XN - 1);
        int gyc = min(max(gy, 0), XN - 1);
        int idx = h * 2 + rs;
        offb[idx] = ((gzc * XN + gyc) * XN + gxc) * 4;
        mc[idx] = (rv && s == 0)  ? 1.f : 0.f;
        ml[idx] = (rv && s == 1)  ? 1.f : 0.f;
        mr[idx] = (rv && s == -1) ? 1.f : 0.f;
    }
    const char* wfp = (const char*)wfrag + lane * 16;

    float4v acc0 = {0.f, 0.f, 0.f, 0.f};
    float4v acc1 = {0.f, 0.f, 0.f, 0.f};
    float dp = 0.f;
    float4v tA[4], tB[4];
    short8v wA[4], wB[4];

#define LOADT(T, W, j) do {                                                  \
    const char* xp = xb + (size_t)(j) * (XVOL * 4);                          \
    _Pragma("unroll")                                                        \
    for (int i5 = 0; i5 < 4; ++i5)                                           \
        T[i5] = ((const f4u*)(xp + offb[i5]))->v;                            \
    const char* wq = wfp + (size_t)(j) * 4096;                               \
    _Pragma("unroll")                                                        \
    for (int i5 = 0; i5 < 4; ++i5)                                           \
        W[i5] = ((const s8u*)(wq + i5 * 1024))->v;                           \
} while (0)

#define COMPT(T, W, j) do {                                                  \
    _Pragma("unroll")                                                        \
    for (int h5 = 0; h5 < 2; ++h5) {                                         \
        float4v r0 = shmask(T[h5 * 2],     mc[h5 * 2],     ml[h5 * 2],     mr[h5 * 2]);     \
        float4v r1 = shmask(T[h5 * 2 + 1], mc[h5 * 2 + 1], ml[h5 * 2 + 1], mr[h5 * 2 + 1]); \
        const float4v wlo = *(const float4v*)&wsl[((j) * 2 + h5) * 32 + g * 8];     \
        const float4v whi = *(const float4v*)&wsl[((j) * 2 + h5) * 32 + g * 8 + 4]; \
        dp = fmaf(wlo[0], r0[0], dp); dp = fmaf(wlo[1], r0[1], dp);          \
        dp = fmaf(wlo[2], r0[2], dp); dp = fmaf(wlo[3], r0[3], dp);          \
        dp = fmaf(whi[0], r1[0], dp); dp = fmaf(whi[1], r1[1], dp);          \
        dp = fmaf(whi[2], r1[2], dp); dp = fmaf(whi[3], r1[3], dp);          \
        union { short8v s; unsigned u[4]; } Bv;                              \
        Bv.u[0] = pk2(r0[0], r0[1]); Bv.u[1] = pk2(r0[2], r0[3]);            \
        Bv.u[2] = pk2(r1[0], r1[1]); Bv.u[3] = pk2(r1[2], r1[3]);            \
        acc0 = __builtin_amdgcn_mfma_f32_16x16x32_bf16(W[h5 * 2],     Bv.s, acc0, 0, 0, 0); \
        acc1 = __builtin_amdgcn_mfma_f32_16x16x32_bf16(W[h5 * 2 + 1], Bv.s, acc1, 0, 0, 0); \
    }                                                                        \
} while (0)

    LOADT(tA, wA, 0);
    LOADT(tB, wB, 1);
    for (int ic = 0; ic < C - 2; ic += 2) {
        COMPT(tA, wA, ic);
        LOADT(tA, wA, ic + 2);
        COMPT(tB, wB, ic + 1);
        LOADT(tB, wB, ic + 3);
    }
    COMPT(tA, wA, C - 2);
    COMPT(tB, wB, C - 1);

#undef LOADT
#undef COMPT

    dp += __shfl_xor(dp, 16, 64);
    dp += __shfl_xor(dp, 32, 64);

    int sp = pz * (DN * DN) + py * DN + px;
    float4v b0 = *(const float4v*)&bias[g * 4];
    float4v b1 = *(const float4v*)&bias[16 + g * 4];
    #pragma unroll
    for (int r = 0; r < 4; ++r) {
        int oc0 = g * 4 + r;
        int oc1 = 16 + g * 4 + r;
        Dout[(size_t)(b * C + oc0) * DVOL + sp] = acc0[r] + b0[r];
        Dout[(size_t)(b * C + oc1) * DVOL + sp] = acc1[r] + b1[r];
    }
    if (g == 0)
        Dsum[b * DVOL + sp] = dp + wsl[2048];
}

// ---- K2: 5^3 gaussian, LDS-staged. Block = (4z x 8y x 8x), 256 blocks.
__global__ __launch_bounds__(256) void k_gauss(const float* __restrict__ Dsum,
                                               const float* __restrict__ gaus_w,
                                               float* __restrict__ filt,
                                               float* __restrict__ outg) {
    __shared__ float tg[8 * 12 * 12];   // 1152
    __shared__ float gk[125];
    int bid = blockIdx.x;
    int xt = bid & 3, yt = (bid >> 2) & 3, zt = (bid >> 4) & 7, b = bid >> 7;
    int tid = threadIdx.x;
    if (tid < 125) gk[tid] = gaus_w[tid];   // replicated kernel: [0][0] slice
    const float* Ds = Dsum + b * DVOL;
    for (int i = tid; i < 1152; i += 256) {
        int lx = i % 12; int r = i / 12; int ly = r % 12; int lz = r / 12;
        int gz = zt * 4 - 2 + lz, gy = yt * 8 - 2 + ly, gx = xt * 8 - 2 + lx;
        float v = 0.f;
        if ((unsigned)gz < DN && (unsigned)gy < DN && (unsigned)gx < DN)
            v = Ds[(gz * DN + gy) * DN + gx];
        tg[i] = v;
    }
    __syncthreads();
    int px = tid & 7, py = (tid >> 3) & 7, pz = tid >> 6;
    const float inv31 = 1.f / 31.f;
    float zb = (float)(zt * 4 + pz - 2);
    float yb = (float)(yt * 8 + py - 2);
    float xb = (float)(xt * 8 + px - 2);
    float p = 0.f, a0 = 0.f, a1 = 0.f, a2 = 0.f;
    for (int tz = 0; tz < 5; ++tz)
    for (int ty = 0; ty < 5; ++ty) {
        int base = ((pz + tz) * 12 + py + ty) * 12 + px;
        #pragma unroll
        for (int tx = 0; tx < 5; ++tx) {
            float g = gk[tz * 25 + ty * 5 + tx];
            float v = g * tg[base + tx];
            p += v;
            a0 = fmaf(v, (zb + (float)tz) * inv31, a0);
            a1 = fmaf(v, (yb + (float)ty) * inv31, a1);
            a2 = fmaf(v, (xb + (float)tx) * inv31, a2);
        }
    }
    float denom = p + 1e-6f;
    float f0 = fminf(fmaxf(a0 / denom * 2.f - 1.f, -1.f), 1.f);
    float f1 = fminf(fmaxf(a1 / denom * 2.f - 1.f, -1.f), 1.f);
    float f2 = fminf(fmaxf(a2 / denom * 2.f - 1.f, -1.f), 1.f);
    int sp = ((zt * 4 + pz) * DN + yt * 8 + py) * DN + xt * 8 + px;
    filt[(b * 3 + 0) * DVOL + sp] = f0;
    filt[(b * 3 + 1) * DVOL + sp] = f1;
    filt[(b * 3 + 2) * DVOL + sp] = f2;
    outg[(size_t)(b * DVOL + sp) * 3 + 0] = f0;
    outg[(size_t)(b * DVOL + sp) * 3 + 1] = f1;
    outg[(size_t)(b * DVOL + sp) * 3 + 2] = f2;
}

// ---- K3: trilinear grid sample. 2048 blocks x 128 thr; tile (2z,4y,16x),
// 8 channels per block. XCD chunk = one (b, channel-group), z-major.
__global__ __launch_bounds__(128, 4) void k_sample(const float* __restrict__ x,
                                                   const float* __restrict__ filt,
                                                   float* __restrict__ y) {
    int bid = blockIdx.x;
    int wid = (bid & 7) * 256 + (bid >> 3);   // 2048%8==0, bijective chunk
    int xt = wid & 1;
    int yt = (wid >> 1) & 7;
    int zt = (wid >> 4) & 15;
    int cgrp = (wid >> 8) & 3;
    int b  = wid >> 10;
    int tid = threadIdx.x;
    int px = tid & 15, py = (tid >> 4) & 3, pz = tid >> 6;
    int sp = ((zt * 2 + pz) * DN + yt * 4 + py) * DN + xt * 16 + px;
    const float* fb = filt + b * 3 * DVOL;
    float g0 = fb[sp], g1 = fb[DVOL + sp], g2 = fb[2 * DVOL + sp];

    float ix = ((g0 + 1.0f) * (float)XN - 1.0f) * 0.5f;
    float iy = ((g1 + 1.0f) * (float)XN - 1.0f) * 0.5f;
    float iz = ((g2 + 1.0f) * (float)XN - 1.0f) * 0.5f;
    float x0f = floorf(ix), y0f = floorf(iy), z0f = floorf(iz);
    float wx = ix - x0f, wyf = iy - y0f, wz = iz - z0f;
    int x0 = (int)x0f, y0i = (int)y0f, z0 = (int)z0f;

    int offs[8];
    float wts[8];
    #pragma unroll
    for (int t = 0; t < 8; ++t) {
        int dz = t >> 2, dy = (t >> 1) & 1, dx = t & 1;
        int zc = z0 + dz, yc = y0i + dy, xc = x0 + dx;
        bool valid = (unsigned)zc < (unsigned)XN && (unsigned)yc < (unsigned)XN &&
                     (unsigned)xc < (unsigned)XN;
        int zcl = min(max(zc, 0), XN - 1);
        int ycl = min(max(yc, 0), XN - 1);
        int xcl = min(max(xc, 0), XN - 1);
        offs[t] = zcl * (XN * XN) + ycl * XN + xcl;
        float w = (dz ? wz : 1.f - wz) * (dy ? wyf : 1.f - wyf) * (dx ? wx : 1.f - wx);
        wts[t] = valid ? w : 0.f;
    }

    const float* xc0 = x + (size_t)(b * C + cgrp * 8) * XVOL;
    #pragma unroll
    for (int g = 0; g < 2; ++g) {
        float t[4][8];                       // 32 loads in flight
        #pragma unroll
        for (int j = 0; j < 4; ++j) {
            const float* xb = xc0 + (size_t)(g * 4 + j) * XVOL;
            #pragma unroll
            for (int k = 0; k < 8; ++k) t[j][k] = xb[offs[k]];
        }
        #pragma unroll
        for (int j = 0; j < 4; ++j) {
            float acc = 0.f;
            #pragma unroll
            for (int k = 0; k < 8; ++k) acc = fmaf(wts[k], t[j][k], acc);
            y[(size_t)(b * C + cgrp * 8 + g * 4 + j) * DVOL + sp] = acc;
        }
    }
}

extern "C" void kernel_launch(void* const* d_in, const int* in_sizes, int n_in,
                              void* d_out, int out_size, void* d_ws, size_t ws_size,
                              hipStream_t stream) {
    const float* x      = (const float*)d_in[0];
    const float* conv_w = (const float*)d_in[1];
    const float* conv_b = (const float*)d_in[2];
    const float* gaus_w = (const float*)d_in[3];

    float* out = (float*)d_out;
    float* y_out = out;
    float* D_out = out + (size_t)2097152;
    float* g_out = out + (size_t)4194304;

    float* ws   = (float*)d_ws;
    float* Dsum = ws;                         // 65536 f
    float* filt = ws + 65536;                 // 196608 f
    float* wsum = ws + 262144;                // 2049 f (+pad to 2112)
    unsigned short* wfrag = (unsigned short*)(ws + 264256);  // 65536 u16

    k_prep<<<dim3(512), dim3(256), 0, stream>>>(conv_w, conv_b, wfrag, wsum);
    k_conv_mfma<<<dim3(4096), dim3(64), 0, stream>>>(x, wfrag, wsum, conv_b,
                                                     D_out, Dsum);
    k_gauss<<<dim3(256), dim3(256), 0, stream>>>(Dsum, gaus_w, filt, g_out);
    k_sample<<<dim3(2048), dim3(128), 0, stream>>>(x, filt, y_out);
    (void)in_sizes; (void)n_in; (void)out_size; (void)ws_size;
}

// Round 11
// 99.150 us; speedup vs baseline: 1.5071x; 1.0877x over previous
//
#include <hip/hip_runtime.h>
#include <hip/hip_bf16.h>

// ---------------------------------------------------------------------------
// Def_DownSampling, round 11.
//  * gaus_w identical per (oc,ic) => gaussian path uses channel-summed field.
//  * conv3+avgpool folded to stride-2 4^3 conv (W4), exact algebra.
//  * D via bf16 MFMA; Dsum kept fp32 (fused VALU dot) for the grid path.
//  * R11: conv is VMEM-request-pipe bound (invariant ~65 us across R5-R10).
//    Weights moved off VMEM: 4-wave blocks, per-2-ic LDS double-buffer
//    (coalesced stage, padded chunks -> conflict-free ds_read_b128).
//    Taps keep R10 direct ping-pong. Barrier per 2 ic.
// Outputs: y (2,32,32,32,32) | D (2,32,32,32,32) | grid-mean (2,32,32,32,3)
// ---------------------------------------------------------------------------

#define XN 64
#define DN 32
#define C  32
#define XVOL (XN * XN * XN)   // 262144
#define DVOL (DN * DN * DN)   // 32768

typedef __attribute__((ext_vector_type(8))) short short8v;
typedef __attribute__((ext_vector_type(4))) float float4v;

struct __attribute__((packed, aligned(4))) f4u { float4v v; };
struct __attribute__((packed, aligned(4))) s8u { short8v v; };

static __device__ __forceinline__ short f2bf(float f) {
    union { float f; unsigned u; } v; v.f = f;
    unsigned r = (v.u + 0x7fffu + ((v.u >> 16) & 1u)) >> 16;   // RNE
    return (short)r;
}

static __device__ __forceinline__ unsigned pk2(float a, float b) {
    __hip_bfloat162 h = __float22bfloat162_rn(float2{a, b});
    union { __hip_bfloat162 h2; unsigned u; } cv; cv.h2 = h;
    return cv.u;
}

// shifted-masked taps: out[c] = mc*ld[c] + ml*ld[c-1] + mr*ld[c+1]
static __device__ __forceinline__ float4v shmask(float4v ld, float c, float l, float r) {
    float4v o;
    o[0] = fmaf(r, ld[1], c * ld[0]);
    o[1] = fmaf(l, ld[0], fmaf(r, ld[2], c * ld[1]));
    o[2] = fmaf(l, ld[1], fmaf(r, ld[3], c * ld[2]));
    o[3] = fmaf(l, ld[2], c * ld[3]);
    return o;
}

// W4[ic][u][oc] = (1/8) sum_{s in {0,1}^3} conv_w[oc][ic][u-s]
static __device__ __forceinline__ float w4val(const float* __restrict__ conv_w,
                                              int ic, int u, int oc) {
    int uz = u >> 4, uy = (u >> 2) & 3, ux = u & 3;
    float s = 0.f;
    #pragma unroll
    for (int sz = 0; sz < 2; ++sz) {
        int tz = uz - sz; if (tz < 0 || tz > 2) continue;
        #pragma unroll
        for (int sy = 0; sy < 2; ++sy) {
            int ty = uy - sy; if (ty < 0 || ty > 2) continue;
            #pragma unroll
            for (int sx = 0; sx < 2; ++sx) {
                int tx = ux - sx; if (tx < 0 || tx > 2) continue;
                s += conv_w[(oc * C + ic) * 27 + tz * 9 + ty * 3 + tx];
            }
        }
    }
    return 0.125f * s;
}

// ---- K0: blocks 0..255 pack A-fragments (bf16) + biassum;
//          blocks 256..511 compute wsum[k] = sum_oc W4[k][oc] via shfl tree.
__global__ __launch_bounds__(256) void k_prep(const float* __restrict__ conv_w,
                                              const float* __restrict__ conv_b,
                                              unsigned short* __restrict__ wfrag,
                                              float* __restrict__ wsum) {
    int bid = blockIdx.x;
    int tid = threadIdx.x;
    if (bid < 256) {
        int i = bid * 256 + tid;                // 65536
        int e = i & 7;
        int l = (i >> 3) & 63;
        int sf = i >> 9;
        int f = sf & 1, step = sf >> 1;
        int oc = f * 16 + (l & 15);
        int k = step * 32 + ((l >> 4) * 8 + e);
        float v = w4val(conv_w, k >> 6, k & 63, oc);
        wfrag[i] = (unsigned short)f2bf(v);
        if (i == 0) {
            float s = 0.f;
            for (int o = 0; o < C; ++o) s += conv_b[o];
            wsum[2048] = s;
        }
    } else {
        int i2 = (bid - 256) * 256 + tid;       // 65536 = 2048 k x 32 oc
        int oc = tid & 31;
        int kk = i2 >> 5;
        float v = w4val(conv_w, kk >> 6, kk & 63, oc);
        v += __shfl_xor(v, 1, 64);
        v += __shfl_xor(v, 2, 64);
        v += __shfl_xor(v, 4, 64);
        v += __shfl_xor(v, 8, 64);
        v += __shfl_xor(v, 16, 64);
        if (oc == 0) wsum[kk] = v;
    }
}

// ---- K1: MFMA conv. 1024 blocks x 256 thr (4 waves).
// Wave w = output (zt*2+(w>>1), yt*2+(w&1), xt*16 + col), all 32 oc.
// Weights: LDS double-buffer, 2 ic (8 KB) per stage, all 4 waves share.
// LDS weight layout: buf*8320 + icL*4160 + chunk*1040 + lane*16 (pad kills
// the 1KB-stride 4-way bank conflict).
__global__ __launch_bounds__(256) void k_conv_mfma(
        const float* __restrict__ x, const unsigned short* __restrict__ wfrag,
        const float* __restrict__ wsum, const float* __restrict__ bias,
        float* __restrict__ Dout, float* __restrict__ Dsum) {
    __shared__ float wsl[2112];
    __shared__ char wbuf[2 * 8320];
    int tid = threadIdx.x;
    for (int i = tid; i < 513; i += 256)
        *(float4v*)&wsl[i * 4] = *(const float4v*)&wsum[i * 4];

    int bid = blockIdx.x;
    int wid = (bid & 7) * 128 + (bid >> 3);      // XCD-chunked swizzle (1024%8==0)
    int xt = wid & 1;
    int yt = (wid >> 1) & 15;
    int zt = (wid >> 5) & 15;
    int b  = wid >> 9;
    int w = tid >> 6, lane = tid & 63;
    int col = lane & 15, g = lane >> 4;
    int pz = zt * 2 + (w >> 1), py = yt * 2 + (w & 1), px = xt * 16 + col;

    const char* xb = (const char*)(x + (size_t)b * C * XVOL);
    const char* wfb = (const char*)wfrag;

    // staging addresses (thread-invariant across steps)
    int sdst = (tid >> 6) * 1040 + (tid & 63) * 16;   // icL=0 chunk/lane slot

    // per-lane tap row byte-offsets & shift-masks (ic-invariant)
    int gxb = 2 * px - 1;
    int gxc = min(max(gxb, 0), XN - 4);
    int s = gxc - gxb;                  // +1 at px==0, -1 at px==31, else 0
    int offb[4];
    float mc[4], ml[4], mr[4];
    #pragma unroll
    for (int h = 0; h < 2; ++h)
    #pragma unroll
    for (int rs = 0; rs < 2; ++rs) {
        int gz = 2 * pz - 1 + 2 * h + (g >> 1);
        int gy = 2 * py - 1 + (g & 1) * 2 + rs;
        bool rv = (unsigned)gz < (unsigned)XN && (unsigned)gy < (unsigned)XN;
        int gzc = min(max(gz, 0), XN - 1);
        int gyc = min(max(gy, 0), XN - 1);
        int idx = h * 2 + rs;
        offb[idx] = ((gzc * XN + gyc) * XN + gxc) * 4;
        mc[idx] = (rv && s == 0)  ? 1.f : 0.f;
        ml[idx] = (rv && s == 1)  ? 1.f : 0.f;
        mr[idx] = (rv && s == -1) ? 1.f : 0.f;
    }

    float4v acc0 = {0.f, 0.f, 0.f, 0.f};
    float4v acc1 = {0.f, 0.f, 0.f, 0.f};
    float dp = 0.f;
    float4v tA[4], tB[4];
    short8v sg0, sg1;

#define LOADT(T, j) do {                                                     \
    const char* xp = xb + (size_t)(j) * (XVOL * 4);                          \
    _Pragma("unroll")                                                        \
    for (int i5 = 0; i5 < 4; ++i5)                                           \
        T[i5] = ((const f4u*)(xp + offb[i5]))->v;                            \
} while (0)

#define STAGE_LOAD(st) do {                                                  \
    const char* wp = wfb + (size_t)(st) * 8192 + tid * 16;                   \
    sg0 = ((const s8u*)(wp))->v;                                             \
    sg1 = ((const s8u*)(wp + 4096))->v;                                      \
} while (0)

#define STAGE_WRITE(bf) do {                                                 \
    *(short8v*)(wbuf + (bf) * 8320 + sdst) = sg0;                            \
    *(short8v*)(wbuf + (bf) * 8320 + 4160 + sdst) = sg1;                     \
} while (0)

#define COMPT(T, bf, icL, j) do {                                            \
    _Pragma("unroll")                                                        \
    for (int h5 = 0; h5 < 2; ++h5) {                                         \
        float4v r0 = shmask(T[h5 * 2],     mc[h5 * 2],     ml[h5 * 2],     mr[h5 * 2]);     \
        float4v r1 = shmask(T[h5 * 2 + 1], mc[h5 * 2 + 1], ml[h5 * 2 + 1], mr[h5 * 2 + 1]); \
        const float4v wlo = *(const float4v*)&wsl[((j) * 2 + h5) * 32 + g * 8];     \
        const float4v whi = *(const float4v*)&wsl[((j) * 2 + h5) * 32 + g * 8 + 4]; \
        dp = fmaf(wlo[0], r0[0], dp); dp = fmaf(wlo[1], r0[1], dp);          \
        dp = fmaf(wlo[2], r0[2], dp); dp = fmaf(wlo[3], r0[3], dp);          \
        dp = fmaf(whi[0], r1[0], dp); dp = fmaf(whi[1], r1[1], dp);          \
        dp = fmaf(whi[2], r1[2], dp); dp = fmaf(whi[3], r1[3], dp);          \
        union { short8v s; unsigned u[4]; } Bv;                              \
        Bv.u[0] = pk2(r0[0], r0[1]); Bv.u[1] = pk2(r0[2], r0[3]);            \
        Bv.u[2] = pk2(r1[0], r1[1]); Bv.u[3] = pk2(r1[2], r1[3]);            \
        const char* wl = wbuf + (bf) * 8320 + (icL) * 4160 + lane * 16;      \
        short8v w0 = *(const short8v*)(wl + (h5 * 2) * 1040);                \
        short8v w1 = *(const short8v*)(wl + (h5 * 2 + 1) * 1040);            \
        acc0 = __builtin_amdgcn_mfma_f32_16x16x32_bf16(w0, Bv.s, acc0, 0, 0, 0); \
        acc1 = __builtin_amdgcn_mfma_f32_16x16x32_bf16(w1, Bv.s, acc1, 0, 0, 0); \
    }                                                                        \
} while (0)

    // prologue: stage step 0, load taps ic 0,1
    STAGE_LOAD(0);
    STAGE_WRITE(0);
    LOADT(tA, 0);
    LOADT(tB, 1);
    __syncthreads();

    for (int st = 0; st < 16; ++st) {
        int cur = st & 1;
        if (st < 15) STAGE_LOAD(st + 1);          // issue-early (T14)
        int ic = st * 2;
        COMPT(tA, cur, 0, ic);
        if (ic + 2 < C) LOADT(tA, ic + 2);
        COMPT(tB, cur, 1, ic + 1);
        if (ic + 3 < C) LOADT(tB, ic + 3);
        if (st < 15) {
            STAGE_WRITE(cur ^ 1);                 // write-late
            __syncthreads();
        }
    }

#undef LOADT
#undef STAGE_LOAD
#undef STAGE_WRITE
#undef COMPT

    dp += __shfl_xor(dp, 16, 64);
    dp += __shfl_xor(dp, 32, 64);

    int sp = pz * (DN * DN) + py * DN + px;
    float4v b0 = *(const float4v*)&bias[g * 4];
    float4v b1 = *(const float4v*)&bias[16 + g * 4];
    #pragma unroll
    for (int r = 0; r < 4; ++r) {
        int oc0 = g * 4 + r;
        int oc1 = 16 + g * 4 + r;
        Dout[(size_t)(b * C + oc0) * DVOL + sp] = acc0[r] + b0[r];
        Dout[(size_t)(b * C + oc1) * DVOL + sp] = acc1[r] + b1[r];
    }
    if (g == 0)
        Dsum[b * DVOL + sp] = dp + wsl[2048];
}

// ---- K2: 5^3 gaussian, LDS-staged. Block = (4z x 8y x 8x), 256 blocks.
__global__ __launch_bounds__(256) void k_gauss(const float* __restrict__ Dsum,
                                               const float* __restrict__ gaus_w,
                                               float* __restrict__ filt,
                                               float* __restrict__ outg) {
    __shared__ float tg[8 * 12 * 12];   // 1152
    __shared__ float gk[125];
    int bid = blockIdx.x;
    int xt = bid & 3, yt = (bid >> 2) & 3, zt = (bid >> 4) & 7, b = bid >> 7;
    int tid = threadIdx.x;
    if (tid < 125) gk[tid] = gaus_w[tid];   // replicated kernel: [0][0] slice
    const float* Ds = Dsum + b * DVOL;
    for (int i = tid; i < 1152; i += 256) {
        int lx = i % 12; int r = i / 12; int ly = r % 12; int lz = r / 12;
        int gz = zt * 4 - 2 + lz, gy = yt * 8 - 2 + ly, gx = xt * 8 - 2 + lx;
        float v = 0.f;
        if ((unsigned)gz < DN && (unsigned)gy < DN && (unsigned)gx < DN)
            v = Ds[(gz * DN + gy) * DN + gx];
        tg[i] = v;
    }
    __syncthreads();
    int px = tid & 7, py = (tid >> 3) & 7, pz = tid >> 6;
    const float inv31 = 1.f / 31.f;
    float zb = (float)(zt * 4 + pz - 2);
    float yb = (float)(yt * 8 + py - 2);
    float xb = (float)(xt * 8 + px - 2);
    float p = 0.f, a0 = 0.f, a1 = 0.f, a2 = 0.f;
    for (int tz = 0; tz < 5; ++tz)
    for (int ty = 0; ty < 5; ++ty) {
        int base = ((pz + tz) * 12 + py + ty) * 12 + px;
        #pragma unroll
        for (int tx = 0; tx < 5; ++tx) {
            float g = gk[tz * 25 + ty * 5 + tx];
            float v = g * tg[base + tx];
            p += v;
            a0 = fmaf(v, (zb + (float)tz) * inv31, a0);
            a1 = fmaf(v, (yb + (float)ty) * inv31, a1);
            a2 = fmaf(v, (xb + (float)tx) * inv31, a2);
        }
    }
    float denom = p + 1e-6f;
    float f0 = fminf(fmaxf(a0 / denom * 2.f - 1.f, -1.f), 1.f);
    float f1 = fminf(fmaxf(a1 / denom * 2.f - 1.f, -1.f), 1.f);
    float f2 = fminf(fmaxf(a2 / denom * 2.f - 1.f, -1.f), 1.f);
    int sp = ((zt * 4 + pz) * DN + yt * 8 + py) * DN + xt * 8 + px;
    filt[(b * 3 + 0) * DVOL + sp] = f0;
    filt[(b * 3 + 1) * DVOL + sp] = f1;
    filt[(b * 3 + 2) * DVOL + sp] = f2;
    outg[(size_t)(b * DVOL + sp) * 3 + 0] = f0;
    outg[(size_t)(b * DVOL + sp) * 3 + 1] = f1;
    outg[(size_t)(b * DVOL + sp) * 3 + 2] = f2;
}

// ---- K3: trilinear grid sample. 2048 blocks x 128 thr; tile (2z,4y,16x),
// 8 channels per block. XCD chunk = one (b, channel-group), z-major.
__global__ __launch_bounds__(128, 4) void k_sample(const float* __restrict__ x,
                                                   const float* __restrict__ filt,
                                                   float* __restrict__ y) {
    int bid = blockIdx.x;
    int wid = (bid & 7) * 256 + (bid >> 3);   // 2048%8==0, bijective chunk
    int xt = wid & 1;
    int yt = (wid >> 1) & 7;
    int zt = (wid >> 4) & 15;
    int cgrp = (wid >> 8) & 3;
    int b  = wid >> 10;
    int tid = threadIdx.x;
    int px = tid & 15, py = (tid >> 4) & 3, pz = tid >> 6;
    int sp = ((zt * 2 + pz) * DN + yt * 4 + py) * DN + xt * 16 + px;
    const float* fb = filt + b * 3 * DVOL;
    float g0 = fb[sp], g1 = fb[DVOL + sp], g2 = fb[2 * DVOL + sp];

    float ix = ((g0 + 1.0f) * (float)XN - 1.0f) * 0.5f;
    float iy = ((g1 + 1.0f) * (float)XN - 1.0f) * 0.5f;
    float iz = ((g2 + 1.0f) * (float)XN - 1.0f) * 0.5f;
    float x0f = floorf(ix), y0f = floorf(iy), z0f = floorf(iz);
    float wx = ix - x0f, wyf = iy - y0f, wz = iz - z0f;
    int x0 = (int)x0f, y0i = (int)y0f, z0 = (int)z0f;

    int offs[8];
    float wts[8];
    #pragma unroll
    for (int t = 0; t < 8; ++t) {
        int dz = t >> 2, dy = (t >> 1) & 1, dx = t & 1;
        int zc = z0 + dz, yc = y0i + dy, xc = x0 + dx;
        bool valid = (unsigned)zc < (unsigned)XN && (unsigned)yc < (unsigned)XN &&
                     (unsigned)xc < (unsigned)XN;
        int zcl = min(max(zc, 0), XN - 1);
        int ycl = min(max(yc, 0), XN - 1);
        int xcl = min(max(xc, 0), XN - 1);
        offs[t] = zcl * (XN * XN) + ycl * XN + xcl;
        float w = (dz ? wz : 1.f - wz) * (dy ? wyf : 1.f - wyf) * (dx ? wx : 1.f - wx);
        wts[t] = valid ? w : 0.f;
    }

    const float* xc0 = x + (size_t)(b * C + cgrp * 8) * XVOL;
    #pragma unroll
    for (int g = 0; g < 2; ++g) {
        float t[4][8];                       // 32 loads in flight
        #pragma unroll
        for (int j = 0; j < 4; ++j) {
            const float* xb = xc0 + (size_t)(g * 4 + j) * XVOL;
            #pragma unroll
            for (int k = 0; k < 8; ++k) t[j][k] = xb[offs[k]];
        }
        #pragma unroll
        for (int j = 0; j < 4; ++j) {
            float acc = 0.f;
            #pragma unroll
            for (int k = 0; k < 8; ++k) acc = fmaf(wts[k], t[j][k], acc);
            y[(size_t)(b * C + cgrp * 8 + g * 4 + j) * DVOL + sp] = acc;
        }
    }
}

extern "C" void kernel_launch(void* const* d_in, const int* in_sizes, int n_in,
                              void* d_out, int out_size, void* d_ws, size_t ws_size,
                              hipStream_t stream) {
    const float* x      = (const float*)d_in[0];
    const float* conv_w = (const float*)d_in[1];
    const float* conv_b = (const float*)d_in[2];
    const float* gaus_w = (const float*)d_in[3];

    float* out = (float*)d_out;
    float* y_out = out;
    float* D_out = out + (size_t)2097152;
    float* g_out = out + (size_t)4194304;

    float* ws   = (float*)d_ws;
    float* Dsum = ws;                         // 65536 f
    float* filt = ws + 65536;                 // 196608 f
    float* wsum = ws + 262144;                // 2049 f (+pad to 2112)
    unsigned short* wfrag = (unsigned short*)(ws + 264256);  // 65536 u16

    k_prep<<<dim3(512), dim3(256), 0, stream>>>(conv_w, conv_b, wfrag, wsum);
    k_conv_mfma<<<dim3(1024), dim3(256), 0, stream>>>(x, wfrag, wsum, conv_b,
                                                      D_out, Dsum);
    k_gauss<<<dim3(256), dim3(256), 0, stream>>>(Dsum, gaus_w, filt, g_out);
    k_sample<<<dim3(2048), dim3(128), 0, stream>>>(x, filt, y_out);
    (void)in_sizes; (void)n_in; (void)out_size; (void)ws_size;
}